// Round 6
// baseline (260.118 us; speedup 1.0000x reference)
//
#include <hip/hip_runtime.h>
#include <cstddef>

// AttentionLayerPooler: out[m,n] = sum_l softmax(logits)[m,l] * in[l,n]
// for in = ks and vs separately. LT=36, LS=28, slice = 2,097,152 fp32.
// Ideal traffic ~1.07 GB -> ~165-175 us floor.
//
// R1-R4: register-resident acc structures stuck at 2 blocks/CU (combined
//   VGPR+AGPR), latency-bound ~285 us; launch_bounds min-waves => spill.
// R5 (LDS tile, one-shot blocks): 229 us. Phase-correlated: stage burst ->
//   barrier -> compute (HBM idle) -> store. HBM duty ~35%, 10.2k cyc/block
//   vs 6.4k floor.
// R6: persistent blocks, depth-2 LDS pipeline. Prefetch tile t+1 via
//   global_load_lds BEFORE computing tile t; one barrier per tile. HBM
//   stream per block is continuous; 2 blocks/CU x 36 KB in flight >> 13 KB
//   latency-BW product. Budget/tile/CU: HBM 6394 cyc >> VALU 2016 >> LDS.

constexpr int LT = 36;                      // teacher layers
constexpr int LS = 28;                      // student layers
constexpr int NELEM = 1 * 16 * 1024 * 128;  // elements per layer slice
constexpr int N2 = NELEM / 2;               // float2 cols per layer (1048576)
constexpr int TILE = 128;                   // float2 cols per tile
constexpr int TPB = 256;                    // 4 waves
constexpr int TILES_PER_TENSOR = N2 / TILE;         // 8192
constexpr int BLOCKS_PER_TENSOR = 512;
constexpr int TILES_PER_BLOCK = TILES_PER_TENSOR / BLOCKS_PER_TENSOR; // 16

__global__ __launch_bounds__(TPB) void pool_kernel(
    const float2* __restrict__ ks,
    const float2* __restrict__ vs,
    const float* __restrict__ lgk,
    const float* __restrict__ lgv,
    float2* __restrict__ out)
{
    // Two staging buffers (depth-2 pipeline) + softmax weights.
    // 2*36 KB + 4 KB = 76 KB -> 2 blocks/CU (152 KB of 160 KB).
    __shared__ float2 smA[LT][TILE];
    __shared__ float2 smB[LT][TILE];
    __shared__ __align__(16) float wl[LS][LT];

    const int tid  = threadIdx.x;
    const int wv   = tid >> 6;        // wave 0..3
    const int lane = tid & 63;

    const bool is_v = (blockIdx.x >= BLOCKS_PER_TENSOR);
    const float* lg = is_v ? lgv : lgk;
    const float2* src = is_v ? vs : ks;
    float2* dst = out + (is_v ? (size_t)LS * N2 : (size_t)0);
    const int blk = is_v ? ((int)blockIdx.x - BLOCKS_PER_TENSOR) : (int)blockIdx.x;
    const int t0  = blk * TILES_PER_BLOCK;  // contiguous tile range per block

    // Stage one 36 KB tile: wave wv loads layers 9wv..9wv+8, one
    // global_load_lds (width 16) per layer row. Zero VGPR data cost.
    auto stage = [&](float2 (*buf)[TILE], int tile) {
        const int c0 = tile * TILE;
#pragma unroll
        for (int j = 0; j < 9; ++j) {
            const int l = 9 * wv + j;
            const float2* g = src + (size_t)l * N2 + c0 + 2 * lane; // 16 B/lane
            __builtin_amdgcn_global_load_lds(
                (const __attribute__((address_space(1))) void*)g,
                (__attribute__((address_space(3))) void*)&buf[l][0],
                16, 0, 0);
        }
    };

    // Prologue: stage tile 0; softmax overlaps the in-flight loads.
    stage(smA, t0);
    if (tid < LS) {
        const float* row = lg + tid * LT;
        float mx = -3.4e38f;
        for (int l = 0; l < LT; ++l) mx = fmaxf(mx, row[l]);
        float s = 0.f;
        for (int l = 0; l < LT; ++l) s += expf(row[l] - mx);
        const float inv = 1.0f / s;
        for (int l = 0; l < LT; ++l) wl[tid][l] = expf(row[l] - mx) * inv;
    }
    __syncthreads();  // buf A ready + wl visible

    float2 (*cur)[TILE] = smA;
    float2 (*nxt)[TILE] = smB;

    const int m0 = 7 * wv;  // wave's 7 output layers

    for (int t = 0; t < TILES_PER_BLOCK; ++t) {
        // 1) Prefetch next tile FIRST -> its HBM latency hides under compute.
        if (t + 1 < TILES_PER_BLOCK) stage(nxt, t0 + t + 1);

        // 2) Compute tile t from cur. Lane owns cols lane, lane+64.
        float2 acc[7][2];
#pragma unroll
        for (int k = 0; k < 7; ++k) {
            acc[k][0] = make_float2(0.f, 0.f);
            acc[k][1] = make_float2(0.f, 0.f);
        }

#pragma unroll
        for (int lb = 0; lb < LT / 4; ++lb) {
            float2 d0[4], d1[4];  // 8 contiguous ds_read_b64, conflict-free
#pragma unroll
            for (int j = 0; j < 4; ++j) {
                d0[j] = cur[4 * lb + j][lane];
                d1[j] = cur[4 * lb + j][lane + 64];
            }
#pragma unroll
            for (int k = 0; k < 7; ++k) {
                // broadcast ds_read_b128 (uniform addr across wave)
                const float4 w = *reinterpret_cast<const float4*>(&wl[m0 + k][4 * lb]);
                acc[k][0].x = fmaf(w.x, d0[0].x, acc[k][0].x);
                acc[k][0].y = fmaf(w.x, d0[0].y, acc[k][0].y);
                acc[k][1].x = fmaf(w.x, d1[0].x, acc[k][1].x);
                acc[k][1].y = fmaf(w.x, d1[0].y, acc[k][1].y);
                acc[k][0].x = fmaf(w.y, d0[1].x, acc[k][0].x);
                acc[k][0].y = fmaf(w.y, d0[1].y, acc[k][0].y);
                acc[k][1].x = fmaf(w.y, d1[1].x, acc[k][1].x);
                acc[k][1].y = fmaf(w.y, d1[1].y, acc[k][1].y);
                acc[k][0].x = fmaf(w.z, d0[2].x, acc[k][0].x);
                acc[k][0].y = fmaf(w.z, d0[2].y, acc[k][0].y);
                acc[k][1].x = fmaf(w.z, d1[2].x, acc[k][1].x);
                acc[k][1].y = fmaf(w.z, d1[2].y, acc[k][1].y);
                acc[k][0].x = fmaf(w.w, d0[3].x, acc[k][0].x);
                acc[k][0].y = fmaf(w.w, d0[3].y, acc[k][0].y);
                acc[k][1].x = fmaf(w.w, d1[3].x, acc[k][1].x);
                acc[k][1].y = fmaf(w.w, d1[3].y, acc[k][1].y);
            }
        }

        // 3) Store tile t: 14 coalesced dwordx2 per lane.
        const int c0 = (t0 + t) * TILE;
#pragma unroll
        for (int k = 0; k < 7; ++k) {
            float2* q = dst + (size_t)(m0 + k) * N2 + c0;
            q[lane]      = acc[k][0];
            q[lane + 64] = acc[k][1];
        }

        // 4) One barrier per tile: drains prefetch (issued a full compute
        // phase ago) + stores; guarantees nobody still reads the buffer
        // that iteration t+1 will overwrite.
        __syncthreads();

        float2 (*tmp)[TILE] = cur; cur = nxt; nxt = tmp;
    }
}

extern "C" void kernel_launch(void* const* d_in, const int* in_sizes, int n_in,
                              void* d_out, int out_size, void* d_ws, size_t ws_size,
                              hipStream_t stream)
{
    const float2* ks  = (const float2*)d_in[0];
    const float2* vs  = (const float2*)d_in[1];
    const float* lgk  = (const float*)d_in[2];
    const float* lgv  = (const float*)d_in[3];
    float2* out = (float2*)d_out;

    dim3 grid(2 * BLOCKS_PER_TENSOR);
    dim3 block(TPB);
    hipLaunchKernelGGL(pool_kernel, grid, block, 0, stream,
                       ks, vs, lgk, lgv, out);
}

// Round 7
// 235.896 us; speedup vs baseline: 1.1027x; 1.1027x over previous
//
#include <hip/hip_runtime.h>
#include <cstddef>

// AttentionLayerPooler: out[m,n] = sum_l softmax(logits)[m,l] * in[l,n]
// for in = ks and vs separately. LT=36, LS=28, slice = 2,097,152 fp32.
// Ideal traffic ~1.07 GB -> ~170 us floor.
//
// R1-R4: reg-resident acc => 2 blocks/CU (AGPR parking), ~285 us;
//        launch_bounds min-waves => scratch spill (NEVER do that here).
// R5 (one-shot LDS tile, 41 KB): 229 us, 3 blocks/CU, but phase-correlated
//        stage->barrier->compute => HBM duty ~45%.
// R6 (depth-2 pipeline, 76 KB LDS): 260 us. Pipeline right, LDS wrong:
//        2 blocks/CU lost more than the pipeline gained.
// R7: depth-2 pipeline at TILE=64 (two 18 KB buffers + 8 KB weights =
//        44.9 KB => 3 blocks/CU). Persistent 768 blocks grid-stride over
//        32768 tiles. Per tile: prefetch-burst next (18 KB in flight),
//        compute cur (504 FMA insts/wave = 1008 cyc), barrier (prefetch &
//        prev stores have had a full compute phase to drain), store after
//        barrier. Per-CU tile floor: HBM 1343 cyc > VALU 1008 cyc.

constexpr int LT = 36;                 // teacher layers
constexpr int LS = 28;                 // student layers
constexpr int N2 = 1048576;            // float2 per layer slice (2,097,152 f32)
constexpr int TILE = 64;               // float2 cols per tile (512 B rows)
constexpr int TPT = N2 / TILE;         // tiles per tensor = 16384 (pow2)
constexpr int NTILES = 2 * TPT;        // 32768
constexpr int TPB = 256;               // 4 waves
constexpr int NBLOCKS = 768;           // 3 resident per CU exactly

__global__ __launch_bounds__(TPB) void pool_kernel(
    const float2* __restrict__ ks,
    const float2* __restrict__ vs,
    const float* __restrict__ lgk,
    const float* __restrict__ lgv,
    float2* __restrict__ out)
{
    // Depth-2 staging buffers (18 KB each, linear [layer][col]) + both
    // softmax tables. 44,928 B total -> 3 blocks/CU.
    __shared__ float2 smA[LT][TILE];
    __shared__ float2 smB[LT][TILE];
    __shared__ __align__(16) float wlK[LS][LT];
    __shared__ __align__(16) float wlV[LS][LT];

    const int tid  = threadIdx.x;
    const int wv   = tid >> 6;   // wave 0..3
    const int lane = tid & 63;

    // Per-lane constant part of the staging source address:
    // chunk c = i*64+lane covers layer l = 2i+(lane>>5), col j = (lane&31)*2.
    const size_t lofs = (size_t)(lane >> 5) * N2 + (size_t)((lane & 31) << 1);

    // Stage one 18 KB tile into buf: 18 wave-instructions total (2 layers
    // per instruction via contiguous LDS), round-robined over 4 waves.
    // LDS dest is wave-uniform; lanes 32-63 land in layer 2i+1. Zero VGPR
    // cost for the data; ~1 KB per instruction in flight.
    auto stage = [&](float2 (*buf)[TILE], int t) {
        const float2* src = (t >= TPT) ? vs : ks;
        const size_t c0 = (size_t)(t & (TPT - 1)) * TILE;
        for (int i = wv; i < 18; i += 4) {
            const float2* g = src + (size_t)(2 * i) * N2 + c0 + lofs;
            __builtin_amdgcn_global_load_lds(
                (const __attribute__((address_space(1))) void*)g,
                (__attribute__((address_space(3))) void*)&buf[2 * i][0],
                16, 0, 0);
        }
    };

    int t = blockIdx.x;

    // Prologue: stage first tile; softmax (both tables) overlaps the
    // in-flight loads. Wave 0 does K rows, wave 1 does V rows.
    stage(smA, t);
    if (wv < 2 && lane < LS) {
        const float* row = (wv == 0 ? lgk : lgv) + lane * LT;
        float (*wl)[LT] = (wv == 0) ? wlK : wlV;
        float mx = -3.4e38f;
        for (int l = 0; l < LT; ++l) mx = fmaxf(mx, row[l]);
        float s = 0.f;
        for (int l = 0; l < LT; ++l) s += expf(row[l] - mx);
        const float inv = 1.0f / s;
        for (int l = 0; l < LT; ++l) wl[lane][l] = expf(row[l] - mx) * inv;
    }
    __syncthreads();  // first tile + weights ready

    float2 (*cur)[TILE] = smA;
    float2 (*nxt)[TILE] = smB;
    const int m0 = 7 * wv;  // wave's 7 output layers

    while (true) {
        const int tn = t + NBLOCKS;
        const bool more = (tn < NTILES);

        // 1) Prefetch next tile FIRST: HBM latency hides under compute.
        if (more) stage(nxt, tn);

        const bool isv = (t >= TPT);
        const float (*wl)[LT] = isv ? wlV : wlK;
        const size_t c0 = (size_t)(t & (TPT - 1)) * TILE;
        float2* dstb = out + (isv ? (size_t)LS * N2 : (size_t)0);

        // 2) Compute tile t from cur. Lane owns one float2 column.
        float2 acc[7];
#pragma unroll
        for (int k = 0; k < 7; ++k) acc[k] = make_float2(0.f, 0.f);

#pragma unroll
        for (int lb = 0; lb < LT / 4; ++lb) {
            float2 d[4];  // 4 contiguous ds_read_b64 (512 B/wave) - conflict-free
#pragma unroll
            for (int j = 0; j < 4; ++j) d[j] = cur[4 * lb + j][lane];
#pragma unroll
            for (int k = 0; k < 7; ++k) {
                // uniform-address ds_read_b128 broadcast
                const float4 w = *reinterpret_cast<const float4*>(&wl[m0 + k][4 * lb]);
                acc[k].x = fmaf(w.x, d[0].x, acc[k].x);
                acc[k].y = fmaf(w.x, d[0].y, acc[k].y);
                acc[k].x = fmaf(w.y, d[1].x, acc[k].x);
                acc[k].y = fmaf(w.y, d[1].y, acc[k].y);
                acc[k].x = fmaf(w.z, d[2].x, acc[k].x);
                acc[k].y = fmaf(w.z, d[2].y, acc[k].y);
                acc[k].x = fmaf(w.w, d[3].x, acc[k].x);
                acc[k].y = fmaf(w.w, d[3].y, acc[k].y);
            }
        }

        // 3) Barrier BEFORE stores: drains the prefetch (issued one full
        // compute phase ago) and last tile's stores; licenses next
        // iteration's stage to overwrite cur.
        __syncthreads();

        // 4) Store tile t after the barrier: drains under next compute.
#pragma unroll
        for (int k = 0; k < 7; ++k) {
            dstb[(size_t)(m0 + k) * N2 + c0 + lane] = acc[k];
        }

        if (!more) break;
        t = tn;
        float2 (*tmp)[TILE] = cur; cur = nxt; nxt = tmp;
    }
}

extern "C" void kernel_launch(void* const* d_in, const int* in_sizes, int n_in,
                              void* d_out, int out_size, void* d_ws, size_t ws_size,
                              hipStream_t stream)
{
    const float2* ks  = (const float2*)d_in[0];
    const float2* vs  = (const float2*)d_in[1];
    const float* lgk  = (const float*)d_in[2];
    const float* lgv  = (const float*)d_in[3];
    float2* out = (float2*)d_out;

    dim3 grid(NBLOCKS);
    dim3 block(TPB);
    hipLaunchKernelGGL(pool_kernel, grid, block, 0, stream,
                       ks, vs, lgk, lgv, out);
}

// Round 8
// 231.684 us; speedup vs baseline: 1.1227x; 1.0182x over previous
//
#include <hip/hip_runtime.h>
#include <cstddef>

// AttentionLayerPooler: out[m,n] = sum_l softmax(logits)[m,l] * in[l,n]
// for in = ks and vs separately. LT=36, LS=28, slice = 2,097,152 fp32.
// Ideal traffic ~1.07 GB -> ~140-170 us floor.
//
// R1-R4: reg-resident acc => 2 blocks/CU, latency-bound ~285 us.
// R5 (one-shot LDS tile): 229 us. R6 (76 KB dbuf): 260 us (2 blocks/CU).
// R7 (depth-2, 45 KB, 3 blocks/CU, __syncthreads): 236 us. Counters show
//   HBM duty ~40%: __syncthreads = s_waitcnt vmcnt(0) + s_barrier drains
//   the ENTIRE vmem queue (incl. next tile's prefetch + prev stores) every
//   iteration -> HBM restarts cold each tile. T4's exact lesson.
// R8: counted vmcnt. Per-wave queue at the pre-compute barrier:
//   loads(t)[4-5] + stores(t-1)[7] + loads(t+1)[4-5]. s_waitcnt vmcnt(11)
//   clears exactly the oldest batch (in-order retire, m135); prefetch and
//   stores stay in flight ACROSS the barrier. Raw s_barrier (no drain).
//   Second raw barrier after compute frees cur for the next DMA overwrite.

constexpr int LT = 36;                 // teacher layers
constexpr int LS = 28;                 // student layers
constexpr int N2 = 1048576;            // float2 per layer slice
constexpr int TILE = 64;               // float2 cols per tile (512 B rows)
constexpr int TPT = N2 / TILE;         // tiles per tensor = 16384 (pow2)
constexpr int NTILES = 2 * TPT;        // 32768
constexpr int TPB = 256;               // 4 waves
constexpr int NBLOCKS = 768;           // 3 resident per CU

__global__ __launch_bounds__(TPB) void pool_kernel(
    const float2* __restrict__ ks,
    const float2* __restrict__ vs,
    const float* __restrict__ lgk,
    const float* __restrict__ lgv,
    float2* __restrict__ out)
{
    // Depth-2 staging buffers (18 KB each, linear [layer][col]) + both
    // softmax tables. ~45 KB -> 3 blocks/CU.
    __shared__ float2 smA[LT][TILE];
    __shared__ float2 smB[LT][TILE];
    __shared__ __align__(16) float wlK[LS][LT];
    __shared__ __align__(16) float wlV[LS][LT];

    const int tid  = threadIdx.x;
    const int wv   = tid >> 6;   // wave 0..3
    const int lane = tid & 63;

    // chunk i covers layers 2i,2i+1: lane L writes LDS base+16L; lanes
    // 32-63 land in row 2i+1. Global side mirrors that layout:
    const size_t lofs = (size_t)(lane >> 5) * N2 + (size_t)((lane & 31) << 1);

    // Stage one 18 KB tile: 18 global_load_lds (width 16) round-robined
    // over 4 waves (waves 0,1: 5 insts; waves 2,3: 4). Zero VGPR data cost.
    auto stage = [&](float2 (*buf)[TILE], int t) {
        const float2* src = (t >= TPT) ? vs : ks;
        const size_t c0 = (size_t)(t & (TPT - 1)) * TILE;
        for (int i = wv; i < 18; i += 4) {
            const float2* g = src + (size_t)(2 * i) * N2 + c0 + lofs;
            __builtin_amdgcn_global_load_lds(
                (const __attribute__((address_space(1))) void*)g,
                (__attribute__((address_space(3))) void*)&buf[2 * i][0],
                16, 0, 0);
        }
    };

    int t = blockIdx.x;

    // Prologue: stage first tile; softmax overlaps in-flight loads.
    stage(smA, t);
    if (wv < 2 && lane < LS) {
        const float* row = (wv == 0 ? lgk : lgv) + lane * LT;
        float (*wl)[LT] = (wv == 0) ? wlK : wlV;
        float mx = -3.4e38f;
        for (int l = 0; l < LT; ++l) mx = fmaxf(mx, row[l]);
        float s = 0.f;
        for (int l = 0; l < LT; ++l) s += expf(row[l] - mx);
        const float inv = 1.0f / s;
        for (int l = 0; l < LT; ++l) wl[lane][l] = expf(row[l] - mx) * inv;
    }
    __syncthreads();  // full drain ONCE: tile 0 + weights ready

    float2 (*cur)[TILE] = smA;
    float2 (*nxt)[TILE] = smB;
    const int m0 = 7 * wv;  // wave's 7 output layers

    for (;;) {
        const int tn = t + NBLOCKS;
        const bool more = (tn < NTILES);

        // A) Prefetch next tile into nxt (freed by barrier E below).
        if (more) stage(nxt, tn);

        // B) Counted wait: clear only the OLDEST batch = loads(t).
        //    Steady queue (w0/1): loads(t)=5, stores(t-1)=7, loads(t+1)=5
        //    -> <=11 leaves prefetch+stores in flight. Tail: no loads(t+1),
        //    need <=7. Then raw s_barrier (no vmcnt(0) drain!).
        if (more) asm volatile("s_waitcnt vmcnt(11)" ::: "memory");
        else      asm volatile("s_waitcnt vmcnt(7)"  ::: "memory");
        __builtin_amdgcn_sched_barrier(0);
        asm volatile("s_barrier" ::: "memory");

        const bool isv = (t >= TPT);
        const float (*wl)[LT] = isv ? wlV : wlK;
        const size_t c0 = (size_t)(t & (TPT - 1)) * TILE;
        float2* dstb = out + (isv ? (size_t)LS * N2 : (size_t)0);

        // C) Compute tile t from cur. Lane owns one float2 column.
        float2 acc[7];
#pragma unroll
        for (int k = 0; k < 7; ++k) acc[k] = make_float2(0.f, 0.f);

#pragma unroll
        for (int lb = 0; lb < LT / 4; ++lb) {
            float2 d[4];  // contiguous ds_read_b64, 2-way bank alias = free
#pragma unroll
            for (int j = 0; j < 4; ++j) d[j] = cur[4 * lb + j][lane];
#pragma unroll
            for (int k = 0; k < 7; ++k) {
                // uniform-address ds_read_b128 broadcast
                const float4 w = *reinterpret_cast<const float4*>(&wl[m0 + k][4 * lb]);
                acc[k].x = fmaf(w.x, d[0].x, acc[k].x);
                acc[k].y = fmaf(w.x, d[0].y, acc[k].y);
                acc[k].x = fmaf(w.y, d[1].x, acc[k].x);
                acc[k].y = fmaf(w.y, d[1].y, acc[k].y);
                acc[k].x = fmaf(w.z, d[2].x, acc[k].x);
                acc[k].y = fmaf(w.z, d[2].y, acc[k].y);
                acc[k].x = fmaf(w.w, d[3].x, acc[k].x);
                acc[k].y = fmaf(w.w, d[3].y, acc[k].y);
            }
        }

        // D) Stores: fire-and-forget, drain under next iteration's compute.
#pragma unroll
        for (int k = 0; k < 7; ++k) {
            dstb[(size_t)(m0 + k) * N2 + c0 + lane] = acc[k];
        }

        if (!more) break;

        // E) Raw barrier: all waves finished reading cur -> next A() may
        //    DMA-overwrite it. No vmem drain attached.
        asm volatile("s_barrier" ::: "memory");

        t = tn;
        float2 (*tmp)[TILE] = cur; cur = nxt; nxt = tmp;
    }
}

extern "C" void kernel_launch(void* const* d_in, const int* in_sizes, int n_in,
                              void* d_out, int out_size, void* d_ws, size_t ws_size,
                              hipStream_t stream)
{
    const float2* ks  = (const float2*)d_in[0];
    const float2* vs  = (const float2*)d_in[1];
    const float* lgk  = (const float*)d_in[2];
    const float* lgv  = (const float*)d_in[3];
    float2* out = (float2*)d_out;

    dim3 grid(NBLOCKS);
    dim3 block(TPB);
    hipLaunchKernelGGL(pool_kernel, grid, block, 0, stream,
                       ks, vs, lgk, lgv, out);
}